// Round 1
// 281.847 us; speedup vs baseline: 1.1221x; 1.1221x over previous
//
#include <hip/hip_runtime.h>
#include <hip/hip_bf16.h>

#define CIN 128
#define COUT 512
#define NEG_SLOPE 0.1f

typedef __bf16 bf16x8 __attribute__((ext_vector_type(8)));
typedef float f32x4 __attribute__((ext_vector_type(4)));

static __device__ __forceinline__ unsigned short f2bf(float f) {
  unsigned int u = __builtin_bit_cast(unsigned int, f);
  unsigned int lsb = (u >> 16) & 1u;
  u += 0x7fffu + lsb;  // round-to-nearest-even
  return (unsigned short)(u >> 16);
}
static __device__ __forceinline__ float bf_lo(unsigned int u) {
  return __builtin_bit_cast(float, u << 16);
}
static __device__ __forceinline__ float bf_hi(unsigned int u) {
  return __builtin_bit_cast(float, u & 0xffff0000u);
}
static __device__ __forceinline__ unsigned int pack2(float lo, float hi) {
  return (unsigned int)f2bf(lo) | ((unsigned int)f2bf(hi) << 16);
}

// ---- Edge dtype probe: int64 stored data has every odd int32 word == 0 ----
__global__ void detect_kernel(const int* __restrict__ raw, int* __restrict__ flag, int E) {
  __shared__ int any_nonzero;
  int tid = threadIdx.x;  // 64 threads
  if (tid == 0) any_nonzero = 0;
  __syncthreads();
  int v1 = raw[2 * tid + 1];
  int v2 = raw[2 * (E / 2) + 2 * tid + 1];
  if (v1 != 0 || v2 != 0) atomicOr(&any_nonzero, 1);
  __syncthreads();
  if (tid == 0) *flag = any_nonzero ? 0 : 1;  // 1 => data is int64
}

// Fused decode + degree count + per-edge rank (atomicAdd's return value is
// the edge's slot within its destination row -> scatter needs no atomics).
__global__ void decode_count_kernel(const int* __restrict__ raw, const int* __restrict__ flag,
                                    int* __restrict__ srcA, int* __restrict__ dstA,
                                    int* __restrict__ rank, int* __restrict__ cnt,
                                    int E, int N) {
  int e = blockIdx.x * blockDim.x + threadIdx.x;
  if (e >= E) return;
  int is64 = *flag;
  int s, d;
  if (is64) {
    int2 sv = ((const int2*)raw)[e];       // 8B vector load, low word = value
    int2 dv = ((const int2*)raw)[E + e];
    s = sv.x;
    d = dv.x;
  } else {
    s = raw[e];
    d = raw[E + e];
  }
  if ((unsigned)s >= (unsigned)N) s = 0;
  if ((unsigned)d >= (unsigned)N) d = 0;
  srcA[e] = s;
  dstA[e] = d;
  rank[e] = atomicAdd(&cnt[d], 1);
}

// xs[row] = dinv[row] * x[row], stored bf16 (256 B per row). dinv recomputed
// inline from cnt (cheap; kills the dinv array + kernel).
__global__ __launch_bounds__(256) void xscale_kernel(const float* __restrict__ x,
                                                     const int* __restrict__ cnt,
                                                     unsigned short* __restrict__ xs, int N) {
  int idx = blockIdx.x * blockDim.x + threadIdx.x;  // one float4 group
  if (idx >= N * (CIN / 4)) return;
  int row = idx >> 5;  // 32 float4 groups per row
  float d = 1.0f / sqrtf((float)(cnt[row] + 1));  // +1 = self-loop
  float4 v = ((const float4*)x)[idx];
  ushort4 o;
  o.x = f2bf(v.x * d); o.y = f2bf(v.y * d); o.z = f2bf(v.z * d); o.w = f2bf(v.w * d);
  ((ushort4*)xs)[idx] = o;
}

// ---- Hierarchical device-wide exclusive scan ----
__global__ __launch_bounds__(256) void scan1_kernel(const int* __restrict__ cnt,
                                                    int* __restrict__ rowptr,
                                                    int* __restrict__ bsum, int N) {
  __shared__ int buf[256];
  int tid = threadIdx.x;
  int base = blockIdx.x * 1024 + tid * 4;
  int v[4];
  int tot = 0;
#pragma unroll
  for (int k = 0; k < 4; ++k) {
    int i = base + k;
    v[k] = (i < N) ? cnt[i] : 0;
    tot += v[k];
  }
  buf[tid] = tot;
  __syncthreads();
  for (int off = 1; off < 256; off <<= 1) {
    int t = (tid >= off) ? buf[tid - off] : 0;
    __syncthreads();
    buf[tid] += t;
    __syncthreads();
  }
  int run = buf[tid] - tot;
  if (tid == 255) bsum[blockIdx.x] = buf[255];
#pragma unroll
  for (int k = 0; k < 4; ++k) {
    int i = base + k;
    if (i < N) rowptr[i] = run;
    run += v[k];
  }
}

__global__ void scan2_kernel(int* __restrict__ bsum, int nb) {
  __shared__ int buf[256];
  int tid = threadIdx.x;
  int v = (tid < nb) ? bsum[tid] : 0;
  buf[tid] = v;
  __syncthreads();
  for (int off = 1; off < 256; off <<= 1) {
    int t = (tid >= off) ? buf[tid - off] : 0;
    __syncthreads();
    buf[tid] += t;
    __syncthreads();
  }
  if (tid < nb) bsum[tid] = buf[tid] - v;
}

__global__ __launch_bounds__(256) void scan3_kernel(int* __restrict__ rowptr,
                                                    const int* __restrict__ bsum, int N) {
  int base = blockIdx.x * 1024 + threadIdx.x * 4;
  int off = bsum[blockIdx.x];
#pragma unroll
  for (int k = 0; k < 4; ++k) {
    int i = base + k;
    if (i < N) rowptr[i] += off;
  }
}

// Atomic-free scatter: slot precomputed in decode (rank).
__global__ void scatter_kernel(const int* __restrict__ srcA, const int* __restrict__ dstA,
                               const int* __restrict__ rank, const int* __restrict__ rowptr,
                               int* __restrict__ col, int E) {
  int e = blockIdx.x * blockDim.x + threadIdx.x;
  if (e < E) col[rowptr[dstA[e]] + rank[e]] = srcA[e];
}

// Gather hop over pre-scaled bf16 rows (256 B/row).
// ONE NODE PER WAVE: lane = (grp 0..3, sub 0..15). Each step the wave pulls 4
// neighbor rows (grp picks the row, sub picks the 16B chunk), so trip count is
// wave-uniform -> no intra-wave degree divergence (was ~25% idle with 4
// nodes/wave on Poisson(16) degrees). Cross-grp reduce via 2x shfl_xor.
// Output: SQ ? di^2 * sum (h1s, feeds next hop) : di * sum (h2, feeds GEMM).
template <bool SQ>
__global__ __launch_bounds__(256) void hop_kernel(
    const unsigned short* __restrict__ Xs,
    const int* __restrict__ rowptr, const int* __restrict__ cnt,
    const int* __restrict__ col, unsigned short* __restrict__ Y, int N) {
  int lane = threadIdx.x & 63;
  int wid = threadIdx.x >> 6;
  int node = blockIdx.x * 4 + wid;
  if (node >= N) return;
  int sub = lane & 15;
  int grp = lane >> 4;
  int beg = rowptr[node];
  int num = cnt[node];
  const uint4* X4 = (const uint4*)Xs;  // one row = 16 uint4
  float acc[8] = {0.f, 0.f, 0.f, 0.f, 0.f, 0.f, 0.f, 0.f};
  if (grp == 0) {  // self-loop term
    uint4 s = X4[(size_t)node * 16 + sub];
    acc[0] = bf_lo(s.x); acc[1] = bf_hi(s.x);
    acc[2] = bf_lo(s.y); acc[3] = bf_hi(s.y);
    acc[4] = bf_lo(s.z); acc[5] = bf_hi(s.z);
    acc[6] = bf_lo(s.w); acc[7] = bf_hi(s.w);
  }
  const int* cp = col + beg;
  int kb = 0;
  // main: 16 rows per step (4 per grp) -> 4 outstanding row loads per lane
  for (; kb + 16 <= num; kb += 16) {
    int j0 = cp[kb + grp];
    int j1 = cp[kb + 4 + grp];
    int j2 = cp[kb + 8 + grp];
    int j3 = cp[kb + 12 + grp];
    uint4 v0 = X4[(size_t)j0 * 16 + sub];
    uint4 v1 = X4[(size_t)j1 * 16 + sub];
    uint4 v2 = X4[(size_t)j2 * 16 + sub];
    uint4 v3 = X4[(size_t)j3 * 16 + sub];
    acc[0] += bf_lo(v0.x); acc[1] += bf_hi(v0.x);
    acc[2] += bf_lo(v0.y); acc[3] += bf_hi(v0.y);
    acc[4] += bf_lo(v0.z); acc[5] += bf_hi(v0.z);
    acc[6] += bf_lo(v0.w); acc[7] += bf_hi(v0.w);
    acc[0] += bf_lo(v1.x); acc[1] += bf_hi(v1.x);
    acc[2] += bf_lo(v1.y); acc[3] += bf_hi(v1.y);
    acc[4] += bf_lo(v1.z); acc[5] += bf_hi(v1.z);
    acc[6] += bf_lo(v1.w); acc[7] += bf_hi(v1.w);
    acc[0] += bf_lo(v2.x); acc[1] += bf_hi(v2.x);
    acc[2] += bf_lo(v2.y); acc[3] += bf_hi(v2.y);
    acc[4] += bf_lo(v2.z); acc[5] += bf_hi(v2.z);
    acc[6] += bf_lo(v2.w); acc[7] += bf_hi(v2.w);
    acc[0] += bf_lo(v3.x); acc[1] += bf_hi(v3.x);
    acc[2] += bf_lo(v3.y); acc[3] += bf_hi(v3.y);
    acc[4] += bf_lo(v3.z); acc[5] += bf_hi(v3.z);
    acc[6] += bf_lo(v3.w); acc[7] += bf_hi(v3.w);
  }
  // tail: 4 rows per step, masked by (k < num) -- num is wave-uniform so this
  // is 16-lane-granular masking only on the last step(s).
  for (; kb < num; kb += 4) {
    int k = kb + grp;
    if (k < num) {
      int j0 = cp[k];
      uint4 v0 = X4[(size_t)j0 * 16 + sub];
      acc[0] += bf_lo(v0.x); acc[1] += bf_hi(v0.x);
      acc[2] += bf_lo(v0.y); acc[3] += bf_hi(v0.y);
      acc[4] += bf_lo(v0.z); acc[5] += bf_hi(v0.z);
      acc[6] += bf_lo(v0.w); acc[7] += bf_hi(v0.w);
    }
  }
  // reduce across the 4 grps (lane bits 4,5)
#pragma unroll
  for (int r = 0; r < 8; ++r) acc[r] += __shfl_xor(acc[r], 16, 64);
#pragma unroll
  for (int r = 0; r < 8; ++r) acc[r] += __shfl_xor(acc[r], 32, 64);
  if (grp == 0) {
    float di = 1.0f / sqrtf((float)(num + 1));
    float sc = SQ ? di * di : di;
    uint4 o;
    o.x = pack2(acc[0] * sc, acc[1] * sc);
    o.y = pack2(acc[2] * sc, acc[3] * sc);
    o.z = pack2(acc[4] * sc, acc[5] * sc);
    o.w = pack2(acc[6] * sc, acc[7] * sc);
    ((uint4*)Y)[(size_t)node * 16 + sub] = o;
  }
}

__global__ void wconv_kernel(const float* __restrict__ W, unsigned short* __restrict__ Wbf, int n) {
  int i = blockIdx.x * blockDim.x + threadIdx.x;
  if (i < n) Wbf[i] = f2bf(W[i]);
}

// y = h2 @ W^T + b, LeakyReLU. Block = 32 rows x full COUT=512.
// Output is 102 MB write-once -> nontemporal stores (don't allocate in cache).
__global__ __launch_bounds__(256) void gemm_kernel(
    const unsigned short* __restrict__ Abf, const unsigned short* __restrict__ Wbf,
    const float* __restrict__ bias, float* __restrict__ out, int M) {
  int wave = threadIdx.x >> 6;
  int lane = threadIdx.x & 63;
  int quad = lane >> 4;
  int l16 = lane & 15;
  int mbase = blockIdx.x * 32;

  bool valid1 = (mbase + 16) < M;

  bf16x8 af[2][4];
#pragma unroll
  for (int kk = 0; kk < 4; ++kk) {
    af[0][kk] = *(const bf16x8*)(Abf + (size_t)(mbase + l16) * CIN + kk * 32 + quad * 8);
    af[1][kk] = valid1
        ? *(const bf16x8*)(Abf + (size_t)(mbase + 16 + l16) * CIN + kk * 32 + quad * 8)
        : bf16x8{};
  }

  int nbase = wave * 128;
#pragma unroll
  for (int nt = 0; nt < 8; ++nt) {
    int n = nbase + nt * 16 + l16;
    const bf16x8* Wrow = (const bf16x8*)(Wbf + (size_t)n * CIN);
    f32x4 acc0 = {}, acc1 = {};
#pragma unroll
    for (int kk = 0; kk < 4; ++kk) {
      bf16x8 bfrag = Wrow[kk * 4 + quad];
      acc0 = __builtin_amdgcn_mfma_f32_16x16x32_bf16(af[0][kk], bfrag, acc0, 0, 0, 0);
      acc1 = __builtin_amdgcn_mfma_f32_16x16x32_bf16(af[1][kk], bfrag, acc1, 0, 0, 0);
    }
    float bv = bias[n];
#pragma unroll
    for (int r = 0; r < 4; ++r) {
      int row0 = mbase + quad * 4 + r;
      float y0 = acc0[r] + bv;
      y0 = (y0 >= 0.f) ? y0 : NEG_SLOPE * y0;
      __builtin_nontemporal_store(y0, &out[(size_t)row0 * COUT + n]);
      if (valid1) {
        float y1 = acc1[r] + bv;
        y1 = (y1 >= 0.f) ? y1 : NEG_SLOPE * y1;
        __builtin_nontemporal_store(y1, &out[(size_t)(row0 + 16) * COUT + n]);
      }
    }
  }
}

static inline size_t align_up(size_t v, size_t a) { return (v + a - 1) & ~(a - 1); }

extern "C" void kernel_launch(void* const* d_in, const int* in_sizes, int n_in,
                              void* d_out, int out_size, void* d_ws, size_t ws_size,
                              hipStream_t stream) {
  const float* x = (const float*)d_in[0];
  const int* edge_raw = (const int*)d_in[1];
  const float* W = (const float*)d_in[2];
  const float* b = (const float*)d_in[3];
  float* out = (float*)d_out;

  const int N = in_sizes[0] / CIN;
  const int E = in_sizes[1] / 2;
  const int NB = (N + 1023) / 1024;  // scan blocks (49 for N=50000)

  // Workspace layout
  char* w = (char*)d_ws;
  int* flag = (int*)w;            w += align_up(sizeof(int), 256);
  int* bsum = (int*)w;            w += align_up(256 * 4, 256);
  int* cnt = (int*)w;             w += align_up((size_t)N * 4, 256);
  int* rowptr = (int*)w;          w += align_up((size_t)N * 4, 256);
  int* srcA = (int*)w;            w += align_up((size_t)E * 4, 256);
  int* dstA = (int*)w;            w += align_up((size_t)E * 4, 256);
  int* rank = (int*)w;            w += align_up((size_t)E * 4, 256);
  int* col = (int*)w;             w += align_up((size_t)E * 4, 256);
  unsigned short* h2bf = (unsigned short*)w;  w += align_up((size_t)N * CIN * 2, 256);
  unsigned short* Wbf = (unsigned short*)w;   w += align_up((size_t)COUT * CIN * 2, 256);

  // bf16 row buffers in the tail of d_out (scratch until GEMM's final write).
  size_t outb = (size_t)out_size * sizeof(float);
  size_t rowb = (size_t)N * CIN * sizeof(unsigned short);
  unsigned short* h1s = (unsigned short*)((char*)d_out + (outb - rowb));
  unsigned short* xs = (unsigned short*)((char*)d_out + (outb - 2 * rowb));

  hipMemsetAsync(cnt, 0, (size_t)N * sizeof(int), stream);

  detect_kernel<<<1, 64, 0, stream>>>(edge_raw, flag, E);
  decode_count_kernel<<<(E + 255) / 256, 256, 0, stream>>>(edge_raw, flag, srcA, dstA, rank, cnt, E, N);
  scan1_kernel<<<NB, 256, 0, stream>>>(cnt, rowptr, bsum, N);
  scan2_kernel<<<1, 256, 0, stream>>>(bsum, NB);
  scan3_kernel<<<NB, 256, 0, stream>>>(rowptr, bsum, N);
  scatter_kernel<<<(E + 255) / 256, 256, 0, stream>>>(srcA, dstA, rank, rowptr, col, E);
  xscale_kernel<<<(N * (CIN / 4) + 255) / 256, 256, 0, stream>>>(x, cnt, xs, N);

  hop_kernel<true><<<(N + 3) / 4, 256, 0, stream>>>(xs, rowptr, cnt, col, h1s, N);
  hop_kernel<false><<<(N + 3) / 4, 256, 0, stream>>>(h1s, rowptr, cnt, col, h2bf, N);

  wconv_kernel<<<(COUT * CIN + 255) / 256, 256, 0, stream>>>(W, Wbf, COUT * CIN);

  gemm_kernel<<<(N + 31) / 32, 256, 0, stream>>>(h2bf, Wbf, b, out, N);
}